// Round 12
// baseline (138.375 us; speedup 1.0000x reference)
//
#include <hip/hip_runtime.h>
#include <hip/hip_bf16.h>

// Problem constants (GCN_66649302499531)
#define NN 20000
#define NG 400
#define D_IN 128
#define H1 256
#define H2 256
#define D_OUT 128
#define WT_ELEMS (D_IN * H1 + H1 * H2 + H2 * D_OUT)   // 131072
#define MCAP 1024   // member-list cap
#define WSLOT 256   // per-wave slice scratch cap (slice mean 6.25)

// LDS strides (elements)
#define STY 72      // Yt feat-major: 256 x 72 bf16 (64 nodes + 8 pad)
#define ST1 136     // T1 node-major: 64 x 128 bf16 (+8 pad)
#define ST2 264     // T2 node-major: 64 x 256 bf16 (+8 pad)
#define ST3 264     // T3 node-major
#define SF  132     // F  node-major: 64 x 128 fp32 (+4 pad)
#define REGB 36864

typedef __attribute__((ext_vector_type(8))) short short8;
typedef __attribute__((ext_vector_type(4))) short short4v;
typedef __attribute__((ext_vector_type(4))) float floatx4;

__device__ __forceinline__ short f2b(float f) {
    __hip_bfloat16 h = __float2bfloat16(f);
    return *(short*)&h;
}

// ---------------------------------------------------------------------------
// Weight transposes fp32 [K][N] -> bf16 [N][K], one launch.
// ---------------------------------------------------------------------------

__global__ __launch_bounds__(256) void wt_all(
    const float* __restrict__ W1, const float* __restrict__ W2,
    const float* __restrict__ W3, __hip_bfloat16* __restrict__ Wt1,
    __hip_bfloat16* __restrict__ Wt2, __hip_bfloat16* __restrict__ Wt3)
{
    int o = blockIdx.x * 256 + threadIdx.x;
    if (o < D_IN * H1) {
        int n = o / D_IN, k = o - n * D_IN;
        Wt1[o] = __float2bfloat16(W1[(size_t)k * H1 + n]);
    } else if (o < D_IN * H1 + H1 * H2) {
        int p = o - D_IN * H1;
        int n = p / H1, k = p - n * H1;
        Wt2[p] = __float2bfloat16(W2[(size_t)k * H2 + n]);
    } else if (o < WT_ELEMS) {
        int p = o - D_IN * H1 - H1 * H2;
        int n = p / H2, k = p - n * H2;
        Wt3[p] = __float2bfloat16(W3[(size_t)k * D_OUT + n]);
    }
}

// ---------------------------------------------------------------------------
// R27: R17 dataflow verbatim, with the two DUPLICATED phase bodies outlined
// into __noinline__ functions emitted once (text ~12KB -> ~7KB). Theory:
// per-block I$ cold-walk (~160 lines x ~200cyc = ~13us) dominates the
// unexplained per-group stall; it uniquely fits R15=R17=R26=53us and
// R18=+6us (second walk warm). Barriers stay in the caller at exact R17
// positions; all register arrays statically indexed (rule #20); carries
// pass/return by value. Prologue/P0/G3/scan3/LN inline verbatim.
// ---------------------------------------------------------------------------

struct Car2 { float4 a, b; };

// G1/G2 shared body: 2 n-tiles/wave, kk rolled (runtime bound kkN).
__device__ __noinline__ void gemm_nt2(
    const short* __restrict__ T, int tstride, int kkN,
    const short* __restrict__ wtp, size_t wstride,
    short* __restrict__ Yt, int w, int lane)
{
    int quad = lane >> 4;
    int l15 = lane & 15;
    floatx4 acc[4][2];
#pragma unroll
    for (int i = 0; i < 4; ++i) { acc[i][0] = (floatx4)0.0f; acc[i][1] = (floatx4)0.0f; }
#pragma clang loop unroll(disable)
    for (int kk = 0; kk < kkN; ++kk) {
        short8 a4[4], bw[2];
#pragma unroll
        for (int i = 0; i < 4; ++i)
            a4[i] = *(const short8*)&T[(i * 16 + l15) * tstride + kk * 32 + quad * 8];
#pragma unroll
        for (int nt = 0; nt < 2; ++nt)
            bw[nt] = *(const short8*)&wtp[((size_t)((w * 2 + nt) * 16 + l15)) * wstride + kk * 32 + quad * 8];
#pragma unroll
        for (int i = 0; i < 4; ++i)
#pragma unroll
            for (int nt = 0; nt < 2; ++nt)
                acc[i][nt] = __builtin_amdgcn_mfma_f32_16x16x32_bf16(
                    a4[i], bw[nt], acc[i][nt], 0, 0, 0);
    }
#pragma unroll
    for (int i = 0; i < 4; ++i)
#pragma unroll
        for (int nt = 0; nt < 2; ++nt) {
            short4v o4;
#pragma unroll
            for (int r = 0; r < 4; ++r) o4[r] = f2b(acc[i][nt][r]);
            *(short4v*)&Yt[((w * 2 + nt) * 16 + l15) * STY + i * 16 + quad * 4] = o4;
        }
}

// scan1/scan2 shared body: 2 feature-tiles/wave; returns updated carries.
__device__ __noinline__ Car2 scan_nt2(
    const short* __restrict__ Yt, short* __restrict__ Tdst, int dstride,
    float4 bbA, float4 bbB, float4 cA, float4 cB,
    int base, int w, int lane)
{
    int quad = lane >> 4;
    int l15 = lane & 15;
    float djn[4];
#pragma unroll
    for (int nt = 0; nt < 4; ++nt)
        djn[nt] = rsqrtf((float)(base + nt * 16 + l15 + 1));
    float cc[2][4] = {{cA.x, cA.y, cA.z, cA.w}, {cB.x, cB.y, cB.z, cB.w}};
    float4 bbv[2] = {bbA, bbB};

    floatx4 acc[2][4];
#pragma unroll
    for (int i = 0; i < 2; ++i)
#pragma unroll
        for (int nt = 0; nt < 4; ++nt) acc[i][nt] = (floatx4)0.0f;
#pragma unroll
    for (int k2 = 0; k2 < 2; ++k2) {
        short8 af[2];
#pragma unroll
        for (int i = 0; i < 2; ++i)
            af[i] = *(const short8*)&Yt[((2 * w + i) * 16 + l15) * STY + k2 * 32 + quad * 8];
#pragma unroll
        for (int nt = 0; nt < 4; ++nt) {
            int thr = nt * 16 + l15 - k2 * 32 - quad * 8;
            short8 lt;
#pragma unroll
            for (int e = 0; e < 8; ++e)
                lt[e] = (e <= thr) ? (short)0x3F80 : (short)0;
#pragma unroll
            for (int i = 0; i < 2; ++i)
                acc[i][nt] = __builtin_amdgcn_mfma_f32_16x16x32_bf16(
                    af[i], lt, acc[i][nt], 0, 0, 0);
        }
    }
#pragma unroll
    for (int i = 0; i < 2; ++i) {
        float nc[4] = {0.f, 0.f, 0.f, 0.f};
#pragma unroll
        for (int nt = 0; nt < 4; ++nt) {
            float tmp[4];
#pragma unroll
            for (int r = 0; r < 4; ++r) tmp[r] = acc[i][nt][r] + cc[i][r];
            if (nt == 3) {
#pragma unroll
                for (int r = 0; r < 4; ++r) nc[r] = tmp[r];
            }
            short4v o4;
            o4[0] = f2b(fmaxf(tmp[0] * djn[nt] + bbv[i].x, 0.0f) * djn[nt]);
            o4[1] = f2b(fmaxf(tmp[1] * djn[nt] + bbv[i].y, 0.0f) * djn[nt]);
            o4[2] = f2b(fmaxf(tmp[2] * djn[nt] + bbv[i].z, 0.0f) * djn[nt]);
            o4[3] = f2b(fmaxf(tmp[3] * djn[nt] + bbv[i].w, 0.0f) * djn[nt]);
            *(short4v*)&Tdst[(nt * 16 + l15) * dstride + (2 * w + i) * 16 + quad * 4] = o4;
        }
#pragma unroll
        for (int r = 0; r < 4; ++r)
            cc[i][r] = __shfl(nc[r], (lane & 48) + 15);
    }
    Car2 outc;
    outc.a = make_float4(cc[0][0], cc[0][1], cc[0][2], cc[0][3]);
    outc.b = make_float4(cc[1][0], cc[1][1], cc[1][2], cc[1][3]);
    return outc;
}

__global__ __launch_bounds__(512) void fused_gcn(
    const float* __restrict__ x, const int* __restrict__ idx,
    const __hip_bfloat16* __restrict__ Wt1_,
    const __hip_bfloat16* __restrict__ Wt2_,
    const __hip_bfloat16* __restrict__ Wt3_,
    const float* __restrict__ b1, const float* __restrict__ b2,
    const float* __restrict__ b3,
    const float* __restrict__ gamma, const float* __restrict__ beta,
    float* __restrict__ out)
{
    __shared__ __align__(16) char RA[REGB];
    __shared__ __align__(16) char RB[REGB];
    __shared__ int mlist[MCAP];
    __shared__ int wcnt[8];

    int tid = threadIdx.x;
    int w = tid >> 6;          // wave 0..7
    int lane = tid & 63;
    int quad = lane >> 4;
    int l15 = lane & 15;
    int g = blockIdx.x;

    // ---- prologue: wave-parallel ordered compaction of group g (verbatim) ----
    int* WS = (int*)RA;   // aliases chunk-0 T1 — dead before first P0 write
    {
        int slice = w * 625;
        int wcount = 0;
        unsigned long long lowm = (1ull << lane) - 1ull;
#pragma unroll
        for (int b2i = 0; b2i < 2; ++b2i) {
            int4 v[5];
#pragma unroll
            for (int r = 0; r < 5; ++r) {
                int q = (b2i * 5 + r) * 64 + lane;
                v[r] = (q < 625) ? *(const int4*)&idx[(slice + q) * 4]
                                 : make_int4(-1, -1, -1, -1);
            }
#pragma unroll
            for (int r = 0; r < 5; ++r) {
                bool f0 = (v[r].x == g), f1 = (v[r].y == g);
                bool f2 = (v[r].z == g), f3 = (v[r].w == g);
                unsigned long long m0 = __ballot(f0), m1 = __ballot(f1);
                unsigned long long m2 = __ballot(f2), m3 = __ballot(f3);
                int p = wcount + __popcll(m0 & lowm) + __popcll(m1 & lowm)
                               + __popcll(m2 & lowm) + __popcll(m3 & lowm);
                int j0 = (slice + (b2i * 5 + r) * 64 + lane) * 4;
                int e0 = (int)f0, e1 = (int)f1, e2 = (int)f2;
                if (f0 && p < WSLOT)                WS[w * WSLOT + p] = j0;
                if (f1 && p + e0 < WSLOT)           WS[w * WSLOT + p + e0] = j0 + 1;
                if (f2 && p + e0 + e1 < WSLOT)      WS[w * WSLOT + p + e0 + e1] = j0 + 2;
                if (f3 && p + e0 + e1 + e2 < WSLOT) WS[w * WSLOT + p + e0 + e1 + e2] = j0 + 3;
                wcount += __popcll(m0) + __popcll(m1) + __popcll(m2) + __popcll(m3);
            }
        }
        if (lane == 0) wcnt[w] = min(wcount, WSLOT);
    }
    __syncthreads();                                   // barrier #1: wcnt
    int cnt = 0;
    {
        int myprefix = 0;
#pragma unroll
        for (int ww = 0; ww < 8; ++ww) {
            int c = wcnt[ww];
            if (ww < w) myprefix += c;
            cnt += c;
        }
        cnt = min(cnt, MCAP);
        int myc = wcnt[w];
        for (int k = lane; k < myc; k += 64) {
            int dstp = myprefix + k;
            if (dstp < MCAP) mlist[dstp] = WS[w * WSLOT + k];
        }
    }
    if (cnt <= 0) return;

    float2 gmv = *(const float2*)&gamma[lane * 2];
    float2 btv = *(const float2*)&beta[lane * 2];
    float4 bb1a = *(const float4*)&b1[(2 * w + 0) * 16 + quad * 4];
    float4 bb1b = *(const float4*)&b1[(2 * w + 1) * 16 + quad * 4];
    float4 bb2a = *(const float4*)&b2[(2 * w + 0) * 16 + quad * 4];
    float4 bb2b = *(const float4*)&b2[(2 * w + 1) * 16 + quad * 4];
    float4 bb3  = *(const float4*)&b3[w * 16 + quad * 4];

    __syncthreads();                                   // barrier #2: mlist ready, WS dead

    // lower-triangular-ones B-frag generator (verified R7..R17)
    auto ltfrag = [&](int nt, int k2) -> short8 {
        int thr = nt * 16 + l15 - k2 * 32 - quad * 8;
        short8 f;
#pragma unroll
        for (int e = 0; e < 8; ++e)
            f[e] = (e <= thr) ? (short)0x3F80 : (short)0;
        return f;
    };

    float4 c1v[2], c2v[2];
    c1v[0] = make_float4(0.f, 0.f, 0.f, 0.f); c1v[1] = c1v[0];
    c2v[0] = c1v[0]; c2v[1] = c1v[0];
    float c3[4] = {0.f, 0.f, 0.f, 0.f};

    // chunk-loop-opaque weight pointers (LICM breaker — R13/R14 evidence)
    const short* wt1p = (const short*)Wt1_;
    const short* wt2p = (const short*)Wt2_;
    const short* wt3p = (const short*)Wt3_;

    for (int base = 0; base < cnt; base += 64) {
        asm("" : "+s"(wt1p), "+s"(wt2p), "+s"(wt3p));
        int mt = min(64, cnt - base);
        int par = (base >> 6) & 1;
        char* Rc = par ? RB : RA;
        char* Rd = par ? RA : RB;
        short* T1 = (short*)Rc;
        short* T2 = (short*)Rc;
        short* T3 = (short*)Rc;
        float* F  = (float*)Rc;
        short* Yt = (short*)Rd;    // feat-major GEMM output (reused x3)

        float djn[4];
#pragma unroll
        for (int nt = 0; nt < 4; ++nt)
            djn[nt] = rsqrtf((float)(base + nt * 16 + l15 + 1));

        // ---- P0: x rows -> T1 = bf16(x * sd), node-major (verbatim) ----
        {
            int row = (lane >> 3) + 8 * w;            // 0..63
            int mr = base + row;
            int nid = mlist[mr < cnt ? mr : cnt - 1];
            float sdr = rsqrtf((float)(mr + 1));
            const float* xp = x + (size_t)nid * D_IN + (lane & 7) * 4;
#pragma unroll
            for (int t = 0; t < 4; ++t) {
                float4 v = *(const float4*)(xp + t * 32);
                short4v o;
                o[0] = f2b(v.x * sdr); o[1] = f2b(v.y * sdr);
                o[2] = f2b(v.z * sdr); o[3] = f2b(v.w * sdr);
                *(short4v*)&T1[row * ST1 + (lane & 7) * 4 + t * 32] = o;
            }
        }
        __syncthreads();   // B1: T1 ready

        gemm_nt2(T1, ST1, 4, wt1p, D_IN, Yt, w, lane);   // G1
        __syncthreads();   // B2: Yt ready, T1 dead

        {
            Car2 r1 = scan_nt2(Yt, T2, ST2, bb1a, bb1b, c1v[0], c1v[1], base, w, lane);
            c1v[0] = r1.a; c1v[1] = r1.b;
        }
        __syncthreads();   // B3: T2 ready, Yt dead

        gemm_nt2(T2, ST2, 8, wt2p, H1, Yt, w, lane);     // G2
        __syncthreads();   // B4: Yt ready, T2 dead

        {
            Car2 r2 = scan_nt2(Yt, T3, ST3, bb2a, bb2b, c2v[0], c2v[1], base, w, lane);
            c2v[0] = r2.a; c2v[1] = r2.b;
        }
        __syncthreads();   // B5: T3 ready, Yt dead

        // ---- G3: Yt = (T3 @ W3^T) feat-major raw; 1 n-tile/wave (verbatim) ----
        {
            floatx4 acc[4];
#pragma unroll
            for (int i = 0; i < 4; ++i) acc[i] = (floatx4)0.0f;
#pragma unroll
            for (int kk = 0; kk < 8; ++kk) {          // K = 256
                short8 bw = *(const short8*)&wt3p[((size_t)(w * 16 + l15)) * H2 + kk * 32 + quad * 8];
#pragma unroll
                for (int i = 0; i < 4; ++i) {
                    short8 a4 = *(const short8*)&T3[(i * 16 + l15) * ST3 + kk * 32 + quad * 8];
                    acc[i] = __builtin_amdgcn_mfma_f32_16x16x32_bf16(a4, bw, acc[i], 0, 0, 0);
                }
            }
#pragma unroll
            for (int i = 0; i < 4; ++i) {
                short4v o4;
#pragma unroll
                for (int r = 0; r < 4; ++r) o4[r] = f2b(acc[i][r]);
                *(short4v*)&Yt[(w * 16 + l15) * STY + i * 16 + quad * 4] = o4;
            }
        }
        __syncthreads();   // B6: Yt ready, T3 dead

        // ---- scan3: F = relu(dj*(c3+cumsum Yt)+b3) fp32; 1 tile/wave (verbatim)
        {
            floatx4 acc[4];
#pragma unroll
            for (int nt = 0; nt < 4; ++nt) acc[nt] = (floatx4)0.0f;
#pragma unroll
            for (int k2 = 0; k2 < 2; ++k2) {
                short8 af = *(const short8*)&Yt[(w * 16 + l15) * STY + k2 * 32 + quad * 8];
#pragma unroll
                for (int nt = 0; nt < 4; ++nt)
                    acc[nt] = __builtin_amdgcn_mfma_f32_16x16x32_bf16(
                        af, ltfrag(nt, k2), acc[nt], 0, 0, 0);
            }
            float nc[4] = {0.f, 0.f, 0.f, 0.f};
#pragma unroll
            for (int nt = 0; nt < 4; ++nt) {
                float tmp[4];
#pragma unroll
                for (int r = 0; r < 4; ++r) tmp[r] = acc[nt][r] + c3[r];
                if (nt == 3) {
#pragma unroll
                    for (int r = 0; r < 4; ++r) nc[r] = tmp[r];
                }
                float4 o;
                o.x = fmaxf(tmp[0] * djn[nt] + bb3.x, 0.0f);
                o.y = fmaxf(tmp[1] * djn[nt] + bb3.y, 0.0f);
                o.z = fmaxf(tmp[2] * djn[nt] + bb3.z, 0.0f);
                o.w = fmaxf(tmp[3] * djn[nt] + bb3.w, 0.0f);
                *(float4*)&F[(nt * 16 + l15) * SF + w * 16 + quad * 4] = o;
            }
#pragma unroll
            for (int r = 0; r < 4; ++r)
                c3[r] = __shfl(nc[r], (lane & 48) + 15);
        }
        __syncthreads();   // B7: F ready, Yt dead

        // ---- LayerNorm rows -> out (verbatim) ----
        for (int r = w; r < mt; r += 8) {
            float2 v = *(const float2*)&F[r * SF + lane * 2];
            float s1 = v.x + v.y;
            float s2v = v.x * v.x + v.y * v.y;
#pragma unroll
            for (int off = 32; off > 0; off >>= 1) {
                s1 += __shfl_down(s1, off);
                s2v += __shfl_down(s2v, off);
            }
            s1 = __shfl(s1, 0);
            s2v = __shfl(s2v, 0);
            float mu = s1 * (1.0f / D_OUT);
            float var = s2v * (1.0f / D_OUT) - mu * mu;
            float rstd = rsqrtf(var + 1e-5f);
            float2 o;
            o.x = (v.x - mu) * rstd * gmv.x + btv.x;
            o.y = (v.y - mu) * rstd * gmv.y + btv.y;
            *(float2*)&out[(size_t)mlist[base + r] * D_OUT + lane * 2] = o;
        }
    }
}

// ---------------------------------------------------------------------------

extern "C" void kernel_launch(void* const* d_in, const int* in_sizes, int n_in,
                              void* d_out, int out_size, void* d_ws, size_t ws_size,
                              hipStream_t stream) {
    const float* x     = (const float*)d_in[0];
    const int*   idx   = (const int*)d_in[1];
    const float* W1    = (const float*)d_in[2];
    const float* b1    = (const float*)d_in[3];
    const float* W2    = (const float*)d_in[4];
    const float* b2    = (const float*)d_in[5];
    const float* W3    = (const float*)d_in[6];
    const float* b3    = (const float*)d_in[7];
    const float* gamma = (const float*)d_in[8];
    const float* beta  = (const float*)d_in[9];
    float* out = (float*)d_out;

    char* ws = (char*)d_ws;
    size_t off = 0;
    auto alloc = [&](size_t bytes) -> void* {
        void* p = (void*)(ws + off);
        off += (bytes + 255) & ~(size_t)255;
        return p;
    };
    __hip_bfloat16* Wt1 = (__hip_bfloat16*)alloc((size_t)D_IN * H1 * 2);
    __hip_bfloat16* Wt2 = (__hip_bfloat16*)alloc((size_t)H1 * H2 * 2);
    __hip_bfloat16* Wt3 = (__hip_bfloat16*)alloc((size_t)H2 * D_OUT * 2);

    wt_all<<<(WT_ELEMS + 255) / 256, 256, 0, stream>>>(
        W1, W2, W3, Wt1, Wt2, Wt3);

    fused_gcn<<<NG, 512, 0, stream>>>(
        x, idx, Wt1, Wt2, Wt3, b1, b2, b3, gamma, beta, out);
}

// Round 13
// 127.403 us; speedup vs baseline: 1.0861x; 1.0861x over previous
//
#include <hip/hip_runtime.h>
#include <hip/hip_bf16.h>

// Problem constants (GCN_66649302499531)
#define NN 20000
#define NG 400
#define D_IN 128
#define H1 256
#define H2 256
#define D_OUT 128
#define MCAP 1024   // member-list cap
#define WSLOT 256   // per-wave slice scratch cap (slice mean 6.25)

// LDS strides (elements)
#define STY 72      // Yt feat-major: 256 x 72 bf16 (64 nodes + 8 pad)
#define ST1 136     // T1 node-major: 64 x 128 bf16 (+8 pad)
#define ST2 264     // T2 node-major: 64 x 256 bf16 (+8 pad)
#define ST3 264     // T3 node-major
#define SF  132     // F  node-major: 64 x 128 fp32 (+4 pad)
#define REGB 36864

typedef __attribute__((ext_vector_type(8))) short short8;
typedef __attribute__((ext_vector_type(4))) short short4v;
typedef __attribute__((ext_vector_type(4))) float floatx4;

__device__ __forceinline__ short f2b(float f) {
    __hip_bfloat16 h = __float2bfloat16(f);
    return *(short*)&h;
}

// ---------------------------------------------------------------------------
// R28 wt_all_t: LDS-tiled weight transpose, fp32 [K][N] -> bf16 [N][K].
// Old wt_all read W at 1KB stride (64 cachelines/wave for 256B useful,
// ~16x over-fetch ~ 8MB, est. 30-50us hidden under the top-5 cutoff).
// Tiled version: coalesced 256B reads -> LDS [64][65] (stride-65 = 2-way
// bank alias, free) -> coalesced bf16 row writes. 32 blocks x 256 thr.
// ---------------------------------------------------------------------------

__global__ __launch_bounds__(256) void wt_all_t(
    const float* __restrict__ W1, const float* __restrict__ W2,
    const float* __restrict__ W3, __hip_bfloat16* __restrict__ Wt1,
    __hip_bfloat16* __restrict__ Wt2, __hip_bfloat16* __restrict__ Wt3)
{
    __shared__ float tile[64][65];

    int bid = blockIdx.x;
    const float* W; __hip_bfloat16* Wt; int K, N, tk, tn;
    if (bid < 8)       { W = W1; Wt = Wt1; K = D_IN; N = H1;
                         tk = bid >> 2;        tn = bid & 3; }        // 2x4
    else if (bid < 24) { W = W2; Wt = Wt2; K = H1;   N = H2;
                         int b = bid - 8;  tk = b >> 2; tn = b & 3; } // 4x4
    else               { W = W3; Wt = Wt3; K = H2;   N = D_OUT;
                         int b = bid - 24; tk = b >> 1; tn = b & 1; } // 4x2

    int t = threadIdx.x;
    int c = t & 63;            // column within tile
    int r0 = t >> 6;           // row group 0..3
    int k0 = tk * 64, n0 = tn * 64;

    // load 64x64 fp32 tile, coalesced over n
#pragma unroll
    for (int it = 0; it < 16; ++it) {
        int r = r0 + it * 4;
        tile[r][c] = W[(size_t)(k0 + r) * N + n0 + c];
    }
    __syncthreads();

    // write transposed bf16, coalesced over k
#pragma unroll
    for (int it = 0; it < 16; ++it) {
        int rn = r0 + it * 4;                      // output row (n)
        Wt[(size_t)(n0 + rn) * K + k0 + c] = __float2bfloat16(tile[c][rn]);
    }
}

// ---------------------------------------------------------------------------
// fused_gcn: R17 verbatim (the verified 53us champion). GEMM-then-scan with
// LDS feat-major transpose; 7 barriers/chunk; RA/RB parity ping-pong.
// ---------------------------------------------------------------------------

__global__ __launch_bounds__(512) void fused_gcn(
    const float* __restrict__ x, const int* __restrict__ idx,
    const __hip_bfloat16* __restrict__ Wt1_,
    const __hip_bfloat16* __restrict__ Wt2_,
    const __hip_bfloat16* __restrict__ Wt3_,
    const float* __restrict__ b1, const float* __restrict__ b2,
    const float* __restrict__ b3,
    const float* __restrict__ gamma, const float* __restrict__ beta,
    float* __restrict__ out)
{
    __shared__ __align__(16) char RA[REGB];
    __shared__ __align__(16) char RB[REGB];
    __shared__ int mlist[MCAP];
    __shared__ int wcnt[8];

    int tid = threadIdx.x;
    int w = tid >> 6;          // wave 0..7
    int lane = tid & 63;
    int quad = lane >> 4;
    int l15 = lane & 15;
    int g = blockIdx.x;

    // ---- prologue: wave-parallel ordered compaction of group g ----
    int* WS = (int*)RA;   // aliases chunk-0 T1 — dead before first P0 write
    {
        int slice = w * 625;
        int wcount = 0;
        unsigned long long lowm = (1ull << lane) - 1ull;
#pragma unroll
        for (int b2i = 0; b2i < 2; ++b2i) {
            int4 v[5];
#pragma unroll
            for (int r = 0; r < 5; ++r) {
                int q = (b2i * 5 + r) * 64 + lane;
                v[r] = (q < 625) ? *(const int4*)&idx[(slice + q) * 4]
                                 : make_int4(-1, -1, -1, -1);
            }
#pragma unroll
            for (int r = 0; r < 5; ++r) {
                bool f0 = (v[r].x == g), f1 = (v[r].y == g);
                bool f2 = (v[r].z == g), f3 = (v[r].w == g);
                unsigned long long m0 = __ballot(f0), m1 = __ballot(f1);
                unsigned long long m2 = __ballot(f2), m3 = __ballot(f3);
                int p = wcount + __popcll(m0 & lowm) + __popcll(m1 & lowm)
                               + __popcll(m2 & lowm) + __popcll(m3 & lowm);
                int j0 = (slice + (b2i * 5 + r) * 64 + lane) * 4;
                int e0 = (int)f0, e1 = (int)f1, e2 = (int)f2;
                if (f0 && p < WSLOT)                WS[w * WSLOT + p] = j0;
                if (f1 && p + e0 < WSLOT)           WS[w * WSLOT + p + e0] = j0 + 1;
                if (f2 && p + e0 + e1 < WSLOT)      WS[w * WSLOT + p + e0 + e1] = j0 + 2;
                if (f3 && p + e0 + e1 + e2 < WSLOT) WS[w * WSLOT + p + e0 + e1 + e2] = j0 + 3;
                wcount += __popcll(m0) + __popcll(m1) + __popcll(m2) + __popcll(m3);
            }
        }
        if (lane == 0) wcnt[w] = min(wcount, WSLOT);
    }
    __syncthreads();                                   // barrier #1: wcnt
    int cnt = 0;
    {
        int myprefix = 0;
#pragma unroll
        for (int ww = 0; ww < 8; ++ww) {
            int c = wcnt[ww];
            if (ww < w) myprefix += c;
            cnt += c;
        }
        cnt = min(cnt, MCAP);
        int myc = wcnt[w];
        for (int k = lane; k < myc; k += 64) {
            int dstp = myprefix + k;
            if (dstp < MCAP) mlist[dstp] = WS[w * WSLOT + k];
        }
    }
    if (cnt <= 0) return;

    float2 gmv = *(const float2*)&gamma[lane * 2];
    float2 btv = *(const float2*)&beta[lane * 2];
    // hoisted per-lane biases (indexed by scan-output feature = quad*4+r)
    float4 bb1[2], bb2[2], bb3;
#pragma unroll
    for (int i = 0; i < 2; ++i) {
        bb1[i] = *(const float4*)&b1[(2 * w + i) * 16 + quad * 4];
        bb2[i] = *(const float4*)&b2[(2 * w + i) * 16 + quad * 4];
    }
    bb3 = *(const float4*)&b3[w * 16 + quad * 4];

    __syncthreads();                                   // barrier #2: mlist ready, WS dead

    // lower-triangular-ones B-frag generator (verified R7..R17)
    auto ltfrag = [&](int nt, int k2) -> short8 {
        int thr = nt * 16 + l15 - k2 * 32 - quad * 8;
        short8 f;
#pragma unroll
        for (int e = 0; e < 8; ++e)
            f[e] = (e <= thr) ? (short)0x3F80 : (short)0;
        return f;
    };

    float c1[2][4], c2[2][4], c3[4];
#pragma unroll
    for (int r = 0; r < 4; ++r) {
        c1[0][r] = 0.f; c1[1][r] = 0.f;
        c2[0][r] = 0.f; c2[1][r] = 0.f;
        c3[r] = 0.f;
    }

    // chunk-loop-opaque weight pointers (LICM breaker — R13/R14 evidence)
    const short* wt1p = (const short*)Wt1_;
    const short* wt2p = (const short*)Wt2_;
    const short* wt3p = (const short*)Wt3_;

    for (int base = 0; base < cnt; base += 64) {
        asm("" : "+s"(wt1p), "+s"(wt2p), "+s"(wt3p));
        int mt = min(64, cnt - base);
        int par = (base >> 6) & 1;
        char* Rc = par ? RB : RA;
        char* Rd = par ? RA : RB;
        short* T1 = (short*)Rc;
        short* T2 = (short*)Rc;
        short* T3 = (short*)Rc;
        float* F  = (float*)Rc;
        short* Yt = (short*)Rd;    // feat-major GEMM output (reused x3)

        float djn[4];
#pragma unroll
        for (int nt = 0; nt < 4; ++nt)
            djn[nt] = rsqrtf((float)(base + nt * 16 + l15 + 1));

        // ---- P0: x rows -> T1 = bf16(x * sd), node-major; reg-staged ----
        {
            int row = (lane >> 3) + 8 * w;            // 0..63
            int mr = base + row;
            int nid = mlist[mr < cnt ? mr : cnt - 1];
            float sdr = rsqrtf((float)(mr + 1));
            const float* xp = x + (size_t)nid * D_IN + (lane & 7) * 4;
#pragma unroll
            for (int t = 0; t < 4; ++t) {
                float4 v = *(const float4*)(xp + t * 32);
                short4v o;
                o[0] = f2b(v.x * sdr); o[1] = f2b(v.y * sdr);
                o[2] = f2b(v.z * sdr); o[3] = f2b(v.w * sdr);
                *(short4v*)&T1[row * ST1 + (lane & 7) * 4 + t * 32] = o;
            }
        }
        __syncthreads();   // B1: T1 ready

        // ---- G1: Yt = (T1 @ W1^T) feat-major raw; 2 n-tiles/wave ----
        {
            floatx4 acc[4][2];
#pragma unroll
            for (int i = 0; i < 4; ++i) { acc[i][0] = (floatx4)0.0f; acc[i][1] = (floatx4)0.0f; }
#pragma unroll
            for (int kk = 0; kk < 4; ++kk) {          // K = 128
                short8 a4[4], bw[2];
#pragma unroll
                for (int i = 0; i < 4; ++i)
                    a4[i] = *(const short8*)&T1[(i * 16 + l15) * ST1 + kk * 32 + quad * 8];
#pragma unroll
                for (int nt = 0; nt < 2; ++nt)
                    bw[nt] = *(const short8*)&wt1p[((size_t)((w * 2 + nt) * 16 + l15)) * D_IN + kk * 32 + quad * 8];
#pragma unroll
                for (int i = 0; i < 4; ++i)
#pragma unroll
                    for (int nt = 0; nt < 2; ++nt)
                        acc[i][nt] = __builtin_amdgcn_mfma_f32_16x16x32_bf16(
                            a4[i], bw[nt], acc[i][nt], 0, 0, 0);
            }
#pragma unroll
            for (int i = 0; i < 4; ++i)
#pragma unroll
                for (int nt = 0; nt < 2; ++nt) {
                    short4v o4;
#pragma unroll
                    for (int r = 0; r < 4; ++r) o4[r] = f2b(acc[i][nt][r]);
                    *(short4v*)&Yt[((w * 2 + nt) * 16 + l15) * STY + i * 16 + quad * 4] = o4;
                }
        }
        __syncthreads();   // B2: Yt ready, T1 dead

        // ---- scan1: T2[j][c] = bf16(relu(dj*(c1+cumsum Yt)+b1)*dj); 2 tiles/wave
        {
            floatx4 acc[2][4];
#pragma unroll
            for (int i = 0; i < 2; ++i)
#pragma unroll
                for (int nt = 0; nt < 4; ++nt) acc[i][nt] = (floatx4)0.0f;
#pragma unroll
            for (int k2 = 0; k2 < 2; ++k2) {
                short8 af[2];
#pragma unroll
                for (int i = 0; i < 2; ++i)
                    af[i] = *(const short8*)&Yt[((2 * w + i) * 16 + l15) * STY + k2 * 32 + quad * 8];
#pragma unroll
                for (int nt = 0; nt < 4; ++nt) {
                    short8 lt = ltfrag(nt, k2);
#pragma unroll
                    for (int i = 0; i < 2; ++i)
                        acc[i][nt] = __builtin_amdgcn_mfma_f32_16x16x32_bf16(
                            af[i], lt, acc[i][nt], 0, 0, 0);
                }
            }
#pragma unroll
            for (int i = 0; i < 2; ++i) {
                float nc[4] = {0.f, 0.f, 0.f, 0.f};
#pragma unroll
                for (int nt = 0; nt < 4; ++nt) {
                    float tmp[4];
#pragma unroll
                    for (int r = 0; r < 4; ++r) tmp[r] = acc[i][nt][r] + c1[i][r];
                    if (nt == 3) {
#pragma unroll
                        for (int r = 0; r < 4; ++r) nc[r] = tmp[r];
                    }
                    short4v o4;
                    o4[0] = f2b(fmaxf(tmp[0] * djn[nt] + bb1[i].x, 0.0f) * djn[nt]);
                    o4[1] = f2b(fmaxf(tmp[1] * djn[nt] + bb1[i].y, 0.0f) * djn[nt]);
                    o4[2] = f2b(fmaxf(tmp[2] * djn[nt] + bb1[i].z, 0.0f) * djn[nt]);
                    o4[3] = f2b(fmaxf(tmp[3] * djn[nt] + bb1[i].w, 0.0f) * djn[nt]);
                    *(short4v*)&T2[(nt * 16 + l15) * ST2 + (2 * w + i) * 16 + quad * 4] = o4;
                }
#pragma unroll
                for (int r = 0; r < 4; ++r)
                    c1[i][r] = __shfl(nc[r], (lane & 48) + 15);
            }
        }
        __syncthreads();   // B3: T2 ready, Yt dead

        // ---- G2: Yt = (T2 @ W2^T) feat-major raw; 2 n-tiles/wave ----
        {
            floatx4 acc[4][2];
#pragma unroll
            for (int i = 0; i < 4; ++i) { acc[i][0] = (floatx4)0.0f; acc[i][1] = (floatx4)0.0f; }
#pragma unroll
            for (int kk = 0; kk < 8; ++kk) {          // K = 256
                short8 a4[4], bw[2];
#pragma unroll
                for (int i = 0; i < 4; ++i)
                    a4[i] = *(const short8*)&T2[(i * 16 + l15) * ST2 + kk * 32 + quad * 8];
#pragma unroll
                for (int nt = 0; nt < 2; ++nt)
                    bw[nt] = *(const short8*)&wt2p[((size_t)((w * 2 + nt) * 16 + l15)) * H1 + kk * 32 + quad * 8];
#pragma unroll
                for (int i = 0; i < 4; ++i)
#pragma unroll
                    for (int nt = 0; nt < 2; ++nt)
                        acc[i][nt] = __builtin_amdgcn_mfma_f32_16x16x32_bf16(
                            a4[i], bw[nt], acc[i][nt], 0, 0, 0);
            }
#pragma unroll
            for (int i = 0; i < 4; ++i)
#pragma unroll
                for (int nt = 0; nt < 2; ++nt) {
                    short4v o4;
#pragma unroll
                    for (int r = 0; r < 4; ++r) o4[r] = f2b(acc[i][nt][r]);
                    *(short4v*)&Yt[((w * 2 + nt) * 16 + l15) * STY + i * 16 + quad * 4] = o4;
                }
        }
        __syncthreads();   // B4: Yt ready, T2 dead

        // ---- scan2: T3[j][c] = bf16(relu(dj*(c2+cumsum Yt)+b2)*dj); 2 tiles/wave
        {
            floatx4 acc[2][4];
#pragma unroll
            for (int i = 0; i < 2; ++i)
#pragma unroll
                for (int nt = 0; nt < 4; ++nt) acc[i][nt] = (floatx4)0.0f;
#pragma unroll
            for (int k2 = 0; k2 < 2; ++k2) {
                short8 af[2];
#pragma unroll
                for (int i = 0; i < 2; ++i)
                    af[i] = *(const short8*)&Yt[((2 * w + i) * 16 + l15) * STY + k2 * 32 + quad * 8];
#pragma unroll
                for (int nt = 0; nt < 4; ++nt) {
                    short8 lt = ltfrag(nt, k2);
#pragma unroll
                    for (int i = 0; i < 2; ++i)
                        acc[i][nt] = __builtin_amdgcn_mfma_f32_16x16x32_bf16(
                            af[i], lt, acc[i][nt], 0, 0, 0);
                }
            }
#pragma unroll
            for (int i = 0; i < 2; ++i) {
                float nc[4] = {0.f, 0.f, 0.f, 0.f};
#pragma unroll
                for (int nt = 0; nt < 4; ++nt) {
                    float tmp[4];
#pragma unroll
                    for (int r = 0; r < 4; ++r) tmp[r] = acc[i][nt][r] + c2[i][r];
                    if (nt == 3) {
#pragma unroll
                        for (int r = 0; r < 4; ++r) nc[r] = tmp[r];
                    }
                    short4v o4;
                    o4[0] = f2b(fmaxf(tmp[0] * djn[nt] + bb2[i].x, 0.0f) * djn[nt]);
                    o4[1] = f2b(fmaxf(tmp[1] * djn[nt] + bb2[i].y, 0.0f) * djn[nt]);
                    o4[2] = f2b(fmaxf(tmp[2] * djn[nt] + bb2[i].z, 0.0f) * djn[nt]);
                    o4[3] = f2b(fmaxf(tmp[3] * djn[nt] + bb2[i].w, 0.0f) * djn[nt]);
                    *(short4v*)&T3[(nt * 16 + l15) * ST3 + (2 * w + i) * 16 + quad * 4] = o4;
                }
#pragma unroll
                for (int r = 0; r < 4; ++r)
                    c2[i][r] = __shfl(nc[r], (lane & 48) + 15);
            }
        }
        __syncthreads();   // B5: T3 ready, Yt dead

        // ---- G3: Yt = (T3 @ W3^T) feat-major raw; 1 n-tile/wave ----
        {
            floatx4 acc[4];
#pragma unroll
            for (int i = 0; i < 4; ++i) acc[i] = (floatx4)0.0f;
#pragma unroll
            for (int kk = 0; kk < 8; ++kk) {          // K = 256
                short8 bw = *(const short8*)&wt3p[((size_t)(w * 16 + l15)) * H2 + kk * 32 + quad * 8];
#pragma unroll
                for (int i = 0; i < 4; ++i) {
                    short8 a4 = *(const short8*)&T3[(i * 16 + l15) * ST3 + kk * 32 + quad * 8];
                    acc[i] = __builtin_amdgcn_mfma_f32_16x16x32_bf16(a4, bw, acc[i], 0, 0, 0);
                }
            }
#pragma unroll
            for (int i = 0; i < 4; ++i) {
                short4v o4;
#pragma unroll
                for (int r = 0; r < 4; ++r) o4[r] = f2b(acc[i][r]);
                *(short4v*)&Yt[(w * 16 + l15) * STY + i * 16 + quad * 4] = o4;
            }
        }
        __syncthreads();   // B6: Yt ready, T3 dead

        // ---- scan3: F[j][d] = relu(dj*(c3+cumsum Yt)+b3) fp32; 1 tile/wave
        {
            floatx4 acc[4];
#pragma unroll
            for (int nt = 0; nt < 4; ++nt) acc[nt] = (floatx4)0.0f;
#pragma unroll
            for (int k2 = 0; k2 < 2; ++k2) {
                short8 af = *(const short8*)&Yt[(w * 16 + l15) * STY + k2 * 32 + quad * 8];
#pragma unroll
                for (int nt = 0; nt < 4; ++nt)
                    acc[nt] = __builtin_amdgcn_mfma_f32_16x16x32_bf16(
                        af, ltfrag(nt, k2), acc[nt], 0, 0, 0);
            }
            float nc[4] = {0.f, 0.f, 0.f, 0.f};
#pragma unroll
            for (int nt = 0; nt < 4; ++nt) {
                float tmp[4];
#pragma unroll
                for (int r = 0; r < 4; ++r) tmp[r] = acc[nt][r] + c3[r];
                if (nt == 3) {
#pragma unroll
                    for (int r = 0; r < 4; ++r) nc[r] = tmp[r];
                }
                float4 o;
                o.x = fmaxf(tmp[0] * djn[nt] + bb3.x, 0.0f);
                o.y = fmaxf(tmp[1] * djn[nt] + bb3.y, 0.0f);
                o.z = fmaxf(tmp[2] * djn[nt] + bb3.z, 0.0f);
                o.w = fmaxf(tmp[3] * djn[nt] + bb3.w, 0.0f);
                *(float4*)&F[(nt * 16 + l15) * SF + w * 16 + quad * 4] = o;
            }
#pragma unroll
            for (int r = 0; r < 4; ++r)
                c3[r] = __shfl(nc[r], (lane & 48) + 15);
        }
        __syncthreads();   // B7: F ready, Yt dead

        // ---- LayerNorm rows -> out (8 waves: rows w, w+8, ...) ----
        for (int r = w; r < mt; r += 8) {
            float2 v = *(const float2*)&F[r * SF + lane * 2];
            float s1 = v.x + v.y;
            float s2v = v.x * v.x + v.y * v.y;
#pragma unroll
            for (int off = 32; off > 0; off >>= 1) {
                s1 += __shfl_down(s1, off);
                s2v += __shfl_down(s2v, off);
            }
            s1 = __shfl(s1, 0);
            s2v = __shfl(s2v, 0);
            float mu = s1 * (1.0f / D_OUT);
            float var = s2v * (1.0f / D_OUT) - mu * mu;
            float rstd = rsqrtf(var + 1e-5f);
            float2 o;
            o.x = (v.x - mu) * rstd * gmv.x + btv.x;
            o.y = (v.y - mu) * rstd * gmv.y + btv.y;
            *(float2*)&out[(size_t)mlist[base + r] * D_OUT + lane * 2] = o;
        }
    }
}

// ---------------------------------------------------------------------------

extern "C" void kernel_launch(void* const* d_in, const int* in_sizes, int n_in,
                              void* d_out, int out_size, void* d_ws, size_t ws_size,
                              hipStream_t stream) {
    const float* x     = (const float*)d_in[0];
    const int*   idx   = (const int*)d_in[1];
    const float* W1    = (const float*)d_in[2];
    const float* b1    = (const float*)d_in[3];
    const float* W2    = (const float*)d_in[4];
    const float* b2    = (const float*)d_in[5];
    const float* W3    = (const float*)d_in[6];
    const float* b3    = (const float*)d_in[7];
    const float* gamma = (const float*)d_in[8];
    const float* beta  = (const float*)d_in[9];
    float* out = (float*)d_out;

    char* ws = (char*)d_ws;
    size_t off = 0;
    auto alloc = [&](size_t bytes) -> void* {
        void* p = (void*)(ws + off);
        off += (bytes + 255) & ~(size_t)255;
        return p;
    };
    __hip_bfloat16* Wt1 = (__hip_bfloat16*)alloc((size_t)D_IN * H1 * 2);
    __hip_bfloat16* Wt2 = (__hip_bfloat16*)alloc((size_t)H1 * H2 * 2);
    __hip_bfloat16* Wt3 = (__hip_bfloat16*)alloc((size_t)H2 * D_OUT * 2);

    wt_all_t<<<32, 256, 0, stream>>>(W1, W2, W3, Wt1, Wt2, Wt3);

    fused_gcn<<<NG, 512, 0, stream>>>(
        x, idx, Wt1, Wt2, Wt3, b1, b2, b3, gamma, beta, out);
}